// Round 6
// baseline (339.570 us; speedup 1.0000x reference)
//
#include <hip/hip_runtime.h>

// MaskedAttentionHead: y = softmax((q@Wq+bq)(k@Wk+bk)^T/8 * m_row) @ (v@Wv+bv)
// B=4 S=4096 D=1024 DK=64. fp32 in/out, bf16 MFMA intermediates, fp32 accum.
// m/8*log2e folded into Q-proj -> mask-free exp2 flash attn, no max-subtract
// (scores statically bounded), additive split-K (4 splits).
// R12: R9 ablation RAN: LDS-free proj = 103us (worse than 79) -> barrier
// skeleton was NOT proj's limiter; revert proj to R8 (78.2us best). Pivot to
// attn_split (never profiled, <78us): its K/V is 4MB L2-resident with 64x
// reuse -> LDS staging + 2 barriers/tile is pure overhead (guide mistake #7).
// Stream K/V from L2 directly into MFMA B-frags (16B/lane coalesced); LDS
// keeps only the wave-private P exchange -> ZERO barriers in attn_split.
// attn_reduce: float4-vectorized.

typedef __attribute__((ext_vector_type(8))) short short8;   // 8 bf16 = MFMA A/B frag
typedef __attribute__((ext_vector_type(4))) float float4v;  // MFMA C/D frag
typedef __attribute__((ext_vector_type(4))) unsigned int uint4v;

#define DEV static __device__ __forceinline__

DEV unsigned short f2bf(float f) {
  unsigned int x; __builtin_memcpy(&x, &f, 4);
  x += 0x7fff + ((x >> 16) & 1);  // round-to-nearest-even
  return (unsigned short)(x >> 16);
}

// ---------------- kernel 1: W transpose (3 x [1024,64] -> [64,1024] bf16) ---
__global__ __launch_bounds__(256) void transpose_w(
    const float* __restrict__ Wq, const float* __restrict__ Wk,
    const float* __restrict__ Wv, unsigned short* __restrict__ WT) {
  int idx = blockIdx.x * 256 + threadIdx.x;   // over 3*1024*64
  int p = idx >> 16;
  int r = idx & 65535;            // r = k*64 + d  (coalesced read)
  int kk = r >> 6, d = r & 63;
  const float* W = (p == 0) ? Wq : (p == 1) ? Wk : Wv;
  WT[p * 65536 + d * 1024 + kk] = f2bf(W[r]);
}

// ---------------- kernel 2: fused projections (32-row tiles, prefetched) ----
// R8 skeleton (best measured 78.2us): LDS-staged, coalesced flat staging,
// register prefetch, 6 blocks/CU.
// p=0: qs[b,s,d]  = (q@Wq+bq) * m[b,s]/8 * log2(e)   (row-major, bf16)
// p=1: kh[b,s,d]  = k@Wk+bk                           (row-major)
// p=2: vhT[b,d,s] = (v@Wv+bv)^T   (transposed via swapped MFMA operand roles)
__global__ __launch_bounds__(256, 6) void proj_kernel(
    const float* __restrict__ xq, const float* __restrict__ xk,
    const float* __restrict__ xv, const float* __restrict__ mmask,
    const float* __restrict__ bq, const float* __restrict__ bk,
    const float* __restrict__ bv, const unsigned short* __restrict__ WT,
    unsigned short* __restrict__ qs, unsigned short* __restrict__ khh,
    unsigned short* __restrict__ vhT) {
  constexpr int LDSTR = 136;  // 128+8: 16B-aligned rows, 2-way bank alias (free)
  __shared__ __align__(16) unsigned short Xs[32 * LDSTR];   //  8704 B
  __shared__ __align__(16) unsigned short Ws[64 * LDSTR];   // 17408 B -> 26.1KB

  const int p = blockIdx.x >> 9;        // projection id (0..2)
  const int rt = blockIdx.x & 511;      // 32-row tile id
  const int row0 = rt * 32;             // flat (b,s) row in [0,16384)
  const int t = threadIdx.x;
  const int w = t >> 6, ln = t & 63;
  const int lr = ln & 15, quad = ln >> 4;

  const float* X = (p == 0) ? xq : (p == 1) ? xk : xv;
  const unsigned short* WTp = WT + p * 65536;
  const float* Xbase = X + (size_t)row0 * 1024;

  float4v acc[2];
#pragma unroll
  for (int i = 0; i < 2; ++i) acc[i] = (float4v){0.f, 0.f, 0.f, 0.f};

  // Coalesced flat-index staging (16 cache lines per wave-instruction):
  //  X chunk = 32 rows x 512B; load i: row i*8+(t>>5), bytes (t&31)*16
  //  W chunk = 64 rows x 256B; load i: row i*16+(t>>4), bytes (t&15)*16
  const int xr_row = t >> 5, xr_col = (t & 31) * 4;   // col in floats
  const int wr_row = t >> 4, wr_col = (t & 15) * 8;   // col in shorts
  const float* Xsrc = Xbase + (size_t)xr_row * 1024 + xr_col;
  const unsigned short* Wsrc = WTp + (size_t)wr_row * 1024 + wr_col;
  unsigned short* Xdst = &Xs[xr_row * LDSTR + xr_col];  // bf16 col == fp32 col idx
  unsigned short* Wdst = &Ws[wr_row * LDSTR + wr_col];

  float4v xr[4];   // prefetch registers: X 64B/thread
  uint4v wr[4];    //                     W 64B/thread

#define ISSUE(kc_)                                                         \
  {                                                                        \
    const int k0_ = (kc_) * 128;                                           \
    _Pragma("unroll") for (int i = 0; i < 4; ++i) {                        \
      xr[i] = *(const float4v*)(Xsrc + (size_t)i * 8 * 1024 + k0_);        \
      wr[i] = *(const uint4v*)(Wsrc + (size_t)i * 16 * 1024 + k0_);       \
    }                                                                      \
  }

  ISSUE(0);
  for (int kc = 0; kc < 8; ++kc) {    // K=1024 in 128-chunks
    // registers -> LDS (convert X to bf16)
#pragma unroll
    for (int i = 0; i < 4; ++i) {
      unsigned short tmp[4];
#pragma unroll
      for (int j = 0; j < 4; ++j) tmp[j] = f2bf(xr[i][j]);
      __builtin_memcpy(Xdst + i * 8 * LDSTR, tmp, 8);
    }
#pragma unroll
    for (int i = 0; i < 4; ++i)
      *(uint4v*)(Wdst + i * 16 * LDSTR) = wr[i];
    __syncthreads();
    if (kc < 7) ISSUE(kc + 1);        // overlap next tile's loads with compute

    if (p < 2) {
      // D[s][d] = X @ W : wave (rb,cb) owns 16 rows x 32 cols
      const int rb = w & 1, cb = w >> 1;
#pragma unroll
      for (int ks = 0; ks < 4; ++ks) {
        short8 af = *(const short8*)&Xs[(rb * 16 + lr) * LDSTR + ks * 32 + quad * 8];
#pragma unroll
        for (int ct = 0; ct < 2; ++ct) {
          short8 bf = *(const short8*)&Ws[(cb * 32 + ct * 16 + lr) * LDSTR + ks * 32 + quad * 8];
          acc[ct] = __builtin_amdgcn_mfma_f32_16x16x32_bf16(af, bf, acc[ct], 0, 0, 0);
        }
      }
    } else {
      // D[d][s] = WT @ X^T : wave w owns 16 d-rows x all 32 s-cols
#pragma unroll
      for (int ks = 0; ks < 4; ++ks) {
        short8 af = *(const short8*)&Ws[(w * 16 + lr) * LDSTR + ks * 32 + quad * 8];
#pragma unroll
        for (int ct = 0; ct < 2; ++ct) {
          short8 bf = *(const short8*)&Xs[(ct * 16 + lr) * LDSTR + ks * 32 + quad * 8];
          acc[ct] = __builtin_amdgcn_mfma_f32_16x16x32_bf16(af, bf, acc[ct], 0, 0, 0);
        }
      }
    }
    __syncthreads();
  }
#undef ISSUE

  // epilogues; C/D layout: col = lr, row = quad*4 + reg
  if (p == 0) {
    const float L2E8 = 1.4426950408889634f * 0.125f;  // log2(e)/sqrt(64)
    const int rb = w & 1, cb = w >> 1;
#pragma unroll
    for (int r = 0; r < 4; ++r) {
      int sg = row0 + rb * 16 + quad * 4 + r;
      float mv = mmask[sg] * L2E8;
#pragma unroll
      for (int ct = 0; ct < 2; ++ct) {
        int d = cb * 32 + ct * 16 + lr;
        qs[(size_t)sg * 64 + d] = f2bf((acc[ct][r] + bq[d]) * mv);
      }
    }
  } else if (p == 1) {
    const int rb = w & 1, cb = w >> 1;
#pragma unroll
    for (int r = 0; r < 4; ++r) {
      int sg = row0 + rb * 16 + quad * 4 + r;
#pragma unroll
      for (int ct = 0; ct < 2; ++ct) {
        int d = cb * 32 + ct * 16 + lr;
        khh[(size_t)sg * 64 + d] = f2bf(acc[ct][r] + bk[d]);
      }
    }
  } else {
    int b = row0 >> 12, sloc = row0 & 4095;
#pragma unroll
    for (int r = 0; r < 4; ++r) {
      int d = w * 16 + quad * 4 + r;
      float bias = bv[d];
#pragma unroll
      for (int ct = 0; ct < 2; ++ct) {
        int sg = sloc + ct * 16 + lr;
        vhT[(size_t)b * 64 * 4096 + (size_t)d * 4096 + sg] = f2bf(acc[ct][r] + bias);
      }
    }
  }
}

// ---------------- kernel 3: split-K flash attention (LDS-free K/V) ---------
// grid = SPLITS * B * (S/64); block = 4 waves, each wave owns 16 q-rows.
// K/V (4MB total, 64x block reuse) stream from L2 directly into MFMA B-frags
// (lane (lr,quad) reads 16B contiguous; 16x64B segments per instr). LDS holds
// only the wave-private P exchange (in-order DS per wave) -> ZERO barriers.
#define SPLITS 4
__global__ __launch_bounds__(256) void attn_split(
    const unsigned short* __restrict__ qs, const unsigned short* __restrict__ khh,
    const unsigned short* __restrict__ vhT, float* __restrict__ O_part,
    float* __restrict__ L_part) {
  constexpr int LDSTR = 88;
  __shared__ __align__(16) unsigned short Ps[4 * 16 * LDSTR];   // per-wave P [q][key]

  const int split = blockIdx.x >> 8;
  const int rest  = blockIdx.x & 255;
  const int b = rest >> 6;
  const int s0 = (rest & 63) * 64;
  const int t = threadIdx.x, w = t >> 6, ln = t & 63;
  const int lr = ln & 15, quad = ln >> 4;

  // Q A-fragments, held in registers for the whole kernel
  const size_t qrow = (size_t)(b * 4096 + s0 + w * 16 + lr) * 64;
  short8 qf0 = *(const short8*)&qs[qrow + quad * 8];
  short8 qf1 = *(const short8*)&qs[qrow + 32 + quad * 8];

  float Lacc[4] = {0.f, 0.f, 0.f, 0.f};
  float4v O[4];
#pragma unroll
  for (int i = 0; i < 4; ++i) O[i] = (float4v){0.f, 0.f, 0.f, 0.f};

  const unsigned short* Kg = khh + (size_t)b * 4096 * 64;
  const unsigned short* Vg = vhT + (size_t)b * 64 * 4096;
  unsigned short* Pw = Ps + w * 16 * LDSTR;

  for (int kt = 0; kt < 16; ++kt) {
    const int k0 = split * 1024 + kt * 64;

    // S = Q K^T: 16 q-rows x 64 keys per wave; K B-frags direct from L2.
    // B-frag: lane (lr,quad) needs kh[k0+ct*16+lr][quad*8 .. +7] (16B contig)
    float4v sc[4];
#pragma unroll
    for (int ct = 0; ct < 4; ++ct) {
      const unsigned short* kb = Kg + (size_t)(k0 + ct * 16 + lr) * 64 + quad * 8;
      short8 kf0 = *(const short8*)kb;
      short8 kf1 = *(const short8*)(kb + 32);
      sc[ct] = (float4v){0.f, 0.f, 0.f, 0.f};
      sc[ct] = __builtin_amdgcn_mfma_f32_16x16x32_bf16(qf0, kf0, sc[ct], 0, 0, 0);
      sc[ct] = __builtin_amdgcn_mfma_f32_16x16x32_bf16(qf1, kf1, sc[ct], 0, 0, 0);
    }

    // P = exp2(S), accumulate per-lane row partials (no shuffles, no rescale)
#pragma unroll
    for (int ct = 0; ct < 4; ++ct)
#pragma unroll
      for (int r = 0; r < 4; ++r) {
        float pv = exp2f(sc[ct][r]);
        Lacc[r] += pv;
        Pw[(quad * 4 + r) * LDSTR + ct * 16 + lr] = f2bf(pv);
      }

    __asm__ volatile("s_waitcnt lgkmcnt(0)" ::: "memory");

    // PV: V^T B-frags direct from L2 (vhT[d][key], 16B contig per lane)
    short8 pf0 = *(const short8*)&Pw[lr * LDSTR + quad * 8];
    short8 pf1 = *(const short8*)&Pw[lr * LDSTR + 32 + quad * 8];
#pragma unroll
    for (int dt = 0; dt < 4; ++dt) {
      const unsigned short* vb = Vg + (size_t)(dt * 16 + lr) * 4096 + k0 + quad * 8;
      short8 vf0 = *(const short8*)vb;
      short8 vf1 = *(const short8*)(vb + 32);
      O[dt] = __builtin_amdgcn_mfma_f32_16x16x32_bf16(pf0, vf0, O[dt], 0, 0, 0);
      O[dt] = __builtin_amdgcn_mfma_f32_16x16x32_bf16(pf1, vf1, O[dt], 0, 0, 0);
    }
  }

  // reduce L over the 16 lanes of each quad (once per kernel, not per tile)
#pragma unroll
  for (int r = 0; r < 4; ++r) {
    float s = Lacc[r];
    s += __shfl_xor(s, 1);
    s += __shfl_xor(s, 2);
    s += __shfl_xor(s, 4);
    s += __shfl_xor(s, 8);
    Lacc[r] = s;
  }

  // store partials; C/D layout: col=lr (d), row=quad*4+r (q-row)
#pragma unroll
  for (int r = 0; r < 4; ++r) {
    int prow = b * 4096 + s0 + w * 16 + quad * 4 + r;
    size_t obase = ((size_t)split * 16384 + prow) * 64;
#pragma unroll
    for (int dt = 0; dt < 4; ++dt)
      O_part[obase + dt * 16 + lr] = O[dt][r];
    if (lr == 0) L_part[(size_t)split * 16384 + prow] = Lacc[r];
  }
}

// ---------------- kernel 4: split-K combine (float4-vectorized) -------------
__global__ __launch_bounds__(256) void attn_reduce(
    const float* __restrict__ O_part, const float* __restrict__ L_part,
    float* __restrict__ out) {
  size_t i4 = (size_t)blockIdx.x * 256 + threadIdx.x;   // over 16384*64/4
  size_t row = i4 >> 4;
  float l = L_part[row] + L_part[16384 + row] + L_part[2 * 16384 + row] +
            L_part[3 * 16384 + row];
  const size_t STRIDE = (size_t)16384 * 64 / 4;         // in float4s
  const float4v* OP = (const float4v*)O_part;
  float4v o = OP[i4];
  float4v o1 = OP[i4 + STRIDE];
  float4v o2 = OP[i4 + 2 * STRIDE];
  float4v o3 = OP[i4 + 3 * STRIDE];
  float inv = 1.0f / l;
  float4v r;
#pragma unroll
  for (int j = 0; j < 4; ++j) r[j] = (o[j] + o1[j] + o2[j] + o3[j]) * inv;
  ((float4v*)out)[i4] = r;
}

// ---------------- launch ----------------------------------------------------
extern "C" void kernel_launch(void* const* d_in, const int* in_sizes, int n_in,
                              void* d_out, int out_size, void* d_ws, size_t ws_size,
                              hipStream_t stream) {
  const float* q  = (const float*)d_in[0];
  const float* k  = (const float*)d_in[1];
  const float* v  = (const float*)d_in[2];
  const float* m  = (const float*)d_in[3];
  const float* Wq = (const float*)d_in[4];
  const float* bq = (const float*)d_in[5];
  const float* Wk = (const float*)d_in[6];
  const float* bk = (const float*)d_in[7];
  const float* Wv = (const float*)d_in[8];
  const float* bv = (const float*)d_in[9];
  float* out = (float*)d_out;

  unsigned short* ws16 = (unsigned short*)d_ws;
  unsigned short* WT  = ws16;                     // 3*65536 u16
  unsigned short* qs  = WT + 3 * 65536;           // 16384*64
  unsigned short* kh  = qs + 16384 * 64;          // 16384*64
  unsigned short* vhT = kh + 16384 * 64;          // 4*64*4096
  float* O_part = (float*)(vhT + 16384 * 64);     // SPLITS*16384*64 fp32 (16.8MB)
  float* L_part = O_part + (size_t)SPLITS * 16384 * 64;  // SPLITS*16384 fp32

  transpose_w<<<dim3(768), dim3(256), 0, stream>>>(Wq, Wk, Wv, WT);
  proj_kernel<<<dim3(1536), dim3(256), 0, stream>>>(q, k, v, m, bq, bk, bv, WT,
                                                    qs, kh, vhT);
  attn_split<<<dim3(SPLITS * 256), dim3(256), 0, stream>>>(qs, kh, vhT,
                                                           O_part, L_part);
  attn_reduce<<<dim3(1024), dim3(256), 0, stream>>>(O_part, L_part, out);
}

// Round 7
// 259.731 us; speedup vs baseline: 1.3074x; 1.3074x over previous
//
#include <hip/hip_runtime.h>

// MaskedAttentionHead: y = softmax((q@Wq+bq)(k@Wk+bk)^T/8 * m_row) @ (v@Wv+bv)
// B=4 S=4096 D=1024 DK=64. fp32 in/out, bf16 MFMA intermediates, fp32 accum.
// m/8*log2e folded into Q-proj -> mask-free exp2 flash attn, no max-subtract
// (scores statically bounded), additive split-K (4 splits).
// R13: R12 ablation: LDS-free attn = 123us (was ~60) -> staging+prefetch
// skeleton is REQUIRED (mirrors R9's proj result). Revert attn to the staged
// skeleton but double reuse: 8 waves / 128 q-rows per block -> staged K/V
// bytes per q-row halve, 1x16B load/thread/buffer, 24 waves/CU (LDS 45KB,
// 3 blocks/CU). proj stays R8 revert (control). float4 reduce kept.

typedef __attribute__((ext_vector_type(8))) short short8;   // 8 bf16 = MFMA A/B frag
typedef __attribute__((ext_vector_type(4))) float float4v;  // MFMA C/D frag
typedef __attribute__((ext_vector_type(4))) unsigned int uint4v;

#define DEV static __device__ __forceinline__

DEV unsigned short f2bf(float f) {
  unsigned int x; __builtin_memcpy(&x, &f, 4);
  x += 0x7fff + ((x >> 16) & 1);  // round-to-nearest-even
  return (unsigned short)(x >> 16);
}

// ---------------- kernel 1: W transpose (3 x [1024,64] -> [64,1024] bf16) ---
__global__ __launch_bounds__(256) void transpose_w(
    const float* __restrict__ Wq, const float* __restrict__ Wk,
    const float* __restrict__ Wv, unsigned short* __restrict__ WT) {
  int idx = blockIdx.x * 256 + threadIdx.x;   // over 3*1024*64
  int p = idx >> 16;
  int r = idx & 65535;            // r = k*64 + d  (coalesced read)
  int kk = r >> 6, d = r & 63;
  const float* W = (p == 0) ? Wq : (p == 1) ? Wk : Wv;
  WT[p * 65536 + d * 1024 + kk] = f2bf(W[r]);
}

// ---------------- kernel 2: fused projections (32-row tiles, prefetched) ----
// R8 skeleton (best measured ~79us): LDS-staged, coalesced flat staging,
// register prefetch, 6 blocks/CU.
__global__ __launch_bounds__(256, 6) void proj_kernel(
    const float* __restrict__ xq, const float* __restrict__ xk,
    const float* __restrict__ xv, const float* __restrict__ mmask,
    const float* __restrict__ bq, const float* __restrict__ bk,
    const float* __restrict__ bv, const unsigned short* __restrict__ WT,
    unsigned short* __restrict__ qs, unsigned short* __restrict__ khh,
    unsigned short* __restrict__ vhT) {
  constexpr int LDSTR = 136;  // 128+8: 16B-aligned rows, 2-way bank alias (free)
  __shared__ __align__(16) unsigned short Xs[32 * LDSTR];   //  8704 B
  __shared__ __align__(16) unsigned short Ws[64 * LDSTR];   // 17408 B -> 26.1KB

  const int p = blockIdx.x >> 9;        // projection id (0..2)
  const int rt = blockIdx.x & 511;      // 32-row tile id
  const int row0 = rt * 32;             // flat (b,s) row in [0,16384)
  const int t = threadIdx.x;
  const int w = t >> 6, ln = t & 63;
  const int lr = ln & 15, quad = ln >> 4;

  const float* X = (p == 0) ? xq : (p == 1) ? xk : xv;
  const unsigned short* WTp = WT + p * 65536;
  const float* Xbase = X + (size_t)row0 * 1024;

  float4v acc[2];
#pragma unroll
  for (int i = 0; i < 2; ++i) acc[i] = (float4v){0.f, 0.f, 0.f, 0.f};

  const int xr_row = t >> 5, xr_col = (t & 31) * 4;   // col in floats
  const int wr_row = t >> 4, wr_col = (t & 15) * 8;   // col in shorts
  const float* Xsrc = Xbase + (size_t)xr_row * 1024 + xr_col;
  const unsigned short* Wsrc = WTp + (size_t)wr_row * 1024 + wr_col;
  unsigned short* Xdst = &Xs[xr_row * LDSTR + xr_col];
  unsigned short* Wdst = &Ws[wr_row * LDSTR + wr_col];

  float4v xr[4];   // prefetch registers: X 64B/thread
  uint4v wr[4];    //                     W 64B/thread

#define ISSUE(kc_)                                                         \
  {                                                                        \
    const int k0_ = (kc_) * 128;                                           \
    _Pragma("unroll") for (int i = 0; i < 4; ++i) {                        \
      xr[i] = *(const float4v*)(Xsrc + (size_t)i * 8 * 1024 + k0_);        \
      wr[i] = *(const uint4v*)(Wsrc + (size_t)i * 16 * 1024 + k0_);       \
    }                                                                      \
  }

  ISSUE(0);
  for (int kc = 0; kc < 8; ++kc) {    // K=1024 in 128-chunks
#pragma unroll
    for (int i = 0; i < 4; ++i) {
      unsigned short tmp[4];
#pragma unroll
      for (int j = 0; j < 4; ++j) tmp[j] = f2bf(xr[i][j]);
      __builtin_memcpy(Xdst + i * 8 * LDSTR, tmp, 8);
    }
#pragma unroll
    for (int i = 0; i < 4; ++i)
      *(uint4v*)(Wdst + i * 16 * LDSTR) = wr[i];
    __syncthreads();
    if (kc < 7) ISSUE(kc + 1);        // overlap next tile's loads with compute

    if (p < 2) {
      const int rb = w & 1, cb = w >> 1;
#pragma unroll
      for (int ks = 0; ks < 4; ++ks) {
        short8 af = *(const short8*)&Xs[(rb * 16 + lr) * LDSTR + ks * 32 + quad * 8];
#pragma unroll
        for (int ct = 0; ct < 2; ++ct) {
          short8 bf = *(const short8*)&Ws[(cb * 32 + ct * 16 + lr) * LDSTR + ks * 32 + quad * 8];
          acc[ct] = __builtin_amdgcn_mfma_f32_16x16x32_bf16(af, bf, acc[ct], 0, 0, 0);
        }
      }
    } else {
#pragma unroll
      for (int ks = 0; ks < 4; ++ks) {
        short8 af = *(const short8*)&Ws[(w * 16 + lr) * LDSTR + ks * 32 + quad * 8];
#pragma unroll
        for (int ct = 0; ct < 2; ++ct) {
          short8 bf = *(const short8*)&Xs[(ct * 16 + lr) * LDSTR + ks * 32 + quad * 8];
          acc[ct] = __builtin_amdgcn_mfma_f32_16x16x32_bf16(af, bf, acc[ct], 0, 0, 0);
        }
      }
    }
    __syncthreads();
  }
#undef ISSUE

  // epilogues; C/D layout: col = lr, row = quad*4 + reg
  if (p == 0) {
    const float L2E8 = 1.4426950408889634f * 0.125f;  // log2(e)/sqrt(64)
    const int rb = w & 1, cb = w >> 1;
#pragma unroll
    for (int r = 0; r < 4; ++r) {
      int sg = row0 + rb * 16 + quad * 4 + r;
      float mv = mmask[sg] * L2E8;
#pragma unroll
      for (int ct = 0; ct < 2; ++ct) {
        int d = cb * 32 + ct * 16 + lr;
        qs[(size_t)sg * 64 + d] = f2bf((acc[ct][r] + bq[d]) * mv);
      }
    }
  } else if (p == 1) {
    const int rb = w & 1, cb = w >> 1;
#pragma unroll
    for (int r = 0; r < 4; ++r) {
      int sg = row0 + rb * 16 + quad * 4 + r;
#pragma unroll
      for (int ct = 0; ct < 2; ++ct) {
        int d = cb * 32 + ct * 16 + lr;
        khh[(size_t)sg * 64 + d] = f2bf(acc[ct][r] + bk[d]);
      }
    }
  } else {
    int b = row0 >> 12, sloc = row0 & 4095;
#pragma unroll
    for (int r = 0; r < 4; ++r) {
      int d = w * 16 + quad * 4 + r;
      float bias = bv[d];
#pragma unroll
      for (int ct = 0; ct < 2; ++ct) {
        int sg = sloc + ct * 16 + lr;
        vhT[(size_t)b * 64 * 4096 + (size_t)d * 4096 + sg] = f2bf(acc[ct][r] + bias);
      }
    }
  }
}

// ---------------- kernel 3: split-K flash attention (staged, 8 waves) ------
// grid = SPLITS * B * (S/128); block = 8 waves = 128 q-rows. Each block
// processes 1024 keys (16 tiles of 64), staging K/V in LDS with one-tile
// register prefetch (the R0 skeleton). Staged bytes per q-row are HALF the
// 4-wave version; staging = exactly one 16B load/thread/buffer.
#define SPLITS 4
__global__ __launch_bounds__(512) void attn_split(
    const unsigned short* __restrict__ qs, const unsigned short* __restrict__ khh,
    const unsigned short* __restrict__ vhT, float* __restrict__ O_part,
    float* __restrict__ L_part) {
  constexpr int LDSTR = 88;
  __shared__ __align__(16) unsigned short Ks[64 * LDSTR];       // [key][d]  11264B
  __shared__ __align__(16) unsigned short Vs[64 * LDSTR];       // [d][key]  11264B
  __shared__ __align__(16) unsigned short Ps[8 * 16 * LDSTR];   // P [q][key] 22528B

  const int split = blockIdx.x >> 7;
  const int rest  = blockIdx.x & 127;
  const int b = rest >> 5;
  const int s0 = (rest & 31) * 128;
  const int t = threadIdx.x, w = t >> 6, ln = t & 63;
  const int lr = ln & 15, quad = ln >> 4;

  // Q A-fragments, held in registers for the whole kernel
  const size_t qrow = (size_t)(b * 4096 + s0 + w * 16 + lr) * 64;
  short8 qf0 = *(const short8*)&qs[qrow + quad * 8];
  short8 qf1 = *(const short8*)&qs[qrow + 32 + quad * 8];

  float Lacc[4] = {0.f, 0.f, 0.f, 0.f};
  float4v O[4];
#pragma unroll
  for (int i = 0; i < 4; ++i) O[i] = (float4v){0.f, 0.f, 0.f, 0.f};

  // staging: 512 threads, 8 threads/row, one 16B chunk each
  const int srow = t >> 3, scol = (t & 7) * 8;
  const unsigned short* Kg = khh + (size_t)b * 4096 * 64;
  const unsigned short* Vg = vhT + (size_t)b * 64 * 4096;
  unsigned short* Pw = Ps + w * 16 * LDSTR;

  uint4v kr, vr;                      // prefetch registers (one each)

#define ISSUE_KV(kt_)                                                       \
  {                                                                         \
    const int k0_ = split * 1024 + (kt_) * 64;                              \
    kr = *(const uint4v*)&Kg[(size_t)(k0_ + srow) * 64 + scol];             \
    vr = *(const uint4v*)&Vg[(size_t)srow * 4096 + k0_ + scol];             \
  }

  ISSUE_KV(0);
  for (int kt = 0; kt < 16; ++kt) {
    *(uint4v*)&Ks[srow * LDSTR + scol] = kr;
    *(uint4v*)&Vs[srow * LDSTR + scol] = vr;
    __syncthreads();
    if (kt < 15) ISSUE_KV(kt + 1);    // overlap next tile's loads with compute

    // S = Q K^T: 16 q-rows x 64 keys per wave
    float4v sc[4];
#pragma unroll
    for (int ct = 0; ct < 4; ++ct) {
      sc[ct] = (float4v){0.f, 0.f, 0.f, 0.f};
      short8 kf0 = *(const short8*)&Ks[(ct * 16 + lr) * LDSTR + quad * 8];
      short8 kf1 = *(const short8*)&Ks[(ct * 16 + lr) * LDSTR + 32 + quad * 8];
      sc[ct] = __builtin_amdgcn_mfma_f32_16x16x32_bf16(qf0, kf0, sc[ct], 0, 0, 0);
      sc[ct] = __builtin_amdgcn_mfma_f32_16x16x32_bf16(qf1, kf1, sc[ct], 0, 0, 0);
    }

    // P = exp2(S), accumulate per-lane row partials (no shuffles, no rescale)
#pragma unroll
    for (int ct = 0; ct < 4; ++ct)
#pragma unroll
      for (int r = 0; r < 4; ++r) {
        float pv = exp2f(sc[ct][r]);
        Lacc[r] += pv;
        Pw[(quad * 4 + r) * LDSTR + ct * 16 + lr] = f2bf(pv);
      }

    __asm__ volatile("s_waitcnt lgkmcnt(0)" ::: "memory");

    short8 pf0 = *(const short8*)&Pw[lr * LDSTR + quad * 8];
    short8 pf1 = *(const short8*)&Pw[lr * LDSTR + 32 + quad * 8];
#pragma unroll
    for (int dt = 0; dt < 4; ++dt) {
      short8 vf0 = *(const short8*)&Vs[(dt * 16 + lr) * LDSTR + quad * 8];
      short8 vf1 = *(const short8*)&Vs[(dt * 16 + lr) * LDSTR + 32 + quad * 8];
      O[dt] = __builtin_amdgcn_mfma_f32_16x16x32_bf16(pf0, vf0, O[dt], 0, 0, 0);
      O[dt] = __builtin_amdgcn_mfma_f32_16x16x32_bf16(pf1, vf1, O[dt], 0, 0, 0);
    }
    __syncthreads();
  }
#undef ISSUE_KV

  // reduce L over the 16 lanes of each quad (once per kernel, not per tile)
#pragma unroll
  for (int r = 0; r < 4; ++r) {
    float s = Lacc[r];
    s += __shfl_xor(s, 1);
    s += __shfl_xor(s, 2);
    s += __shfl_xor(s, 4);
    s += __shfl_xor(s, 8);
    Lacc[r] = s;
  }

  // store partials; C/D layout: col=lr (d), row=quad*4+r (q-row)
#pragma unroll
  for (int r = 0; r < 4; ++r) {
    int prow = b * 4096 + s0 + w * 16 + quad * 4 + r;
    size_t obase = ((size_t)split * 16384 + prow) * 64;
#pragma unroll
    for (int dt = 0; dt < 4; ++dt)
      O_part[obase + dt * 16 + lr] = O[dt][r];
    if (lr == 0) L_part[(size_t)split * 16384 + prow] = Lacc[r];
  }
}

// ---------------- kernel 4: split-K combine (float4-vectorized) -------------
__global__ __launch_bounds__(256) void attn_reduce(
    const float* __restrict__ O_part, const float* __restrict__ L_part,
    float* __restrict__ out) {
  size_t i4 = (size_t)blockIdx.x * 256 + threadIdx.x;   // over 16384*64/4
  size_t row = i4 >> 4;
  float l = L_part[row] + L_part[16384 + row] + L_part[2 * 16384 + row] +
            L_part[3 * 16384 + row];
  const size_t STRIDE = (size_t)16384 * 64 / 4;         // in float4s
  const float4v* OP = (const float4v*)O_part;
  float4v o = OP[i4];
  float4v o1 = OP[i4 + STRIDE];
  float4v o2 = OP[i4 + 2 * STRIDE];
  float4v o3 = OP[i4 + 3 * STRIDE];
  float inv = 1.0f / l;
  float4v r;
#pragma unroll
  for (int j = 0; j < 4; ++j) r[j] = (o[j] + o1[j] + o2[j] + o3[j]) * inv;
  ((float4v*)out)[i4] = r;
}

// ---------------- launch ----------------------------------------------------
extern "C" void kernel_launch(void* const* d_in, const int* in_sizes, int n_in,
                              void* d_out, int out_size, void* d_ws, size_t ws_size,
                              hipStream_t stream) {
  const float* q  = (const float*)d_in[0];
  const float* k  = (const float*)d_in[1];
  const float* v  = (const float*)d_in[2];
  const float* m  = (const float*)d_in[3];
  const float* Wq = (const float*)d_in[4];
  const float* bq = (const float*)d_in[5];
  const float* Wk = (const float*)d_in[6];
  const float* bk = (const float*)d_in[7];
  const float* Wv = (const float*)d_in[8];
  const float* bv = (const float*)d_in[9];
  float* out = (float*)d_out;

  unsigned short* ws16 = (unsigned short*)d_ws;
  unsigned short* WT  = ws16;                     // 3*65536 u16
  unsigned short* qs  = WT + 3 * 65536;           // 16384*64
  unsigned short* kh  = qs + 16384 * 64;          // 16384*64
  unsigned short* vhT = kh + 16384 * 64;          // 4*64*4096
  float* O_part = (float*)(vhT + 16384 * 64);     // SPLITS*16384*64 fp32 (16.8MB)
  float* L_part = O_part + (size_t)SPLITS * 16384 * 64;  // SPLITS*16384 fp32

  transpose_w<<<dim3(768), dim3(256), 0, stream>>>(Wq, Wk, Wv, WT);
  proj_kernel<<<dim3(1536), dim3(256), 0, stream>>>(q, k, v, m, bq, bk, bv, WT,
                                                    qs, kh, vhT);
  attn_split<<<dim3(SPLITS * 128), dim3(512), 0, stream>>>(qs, kh, vhT,
                                                           O_part, L_part);
  attn_reduce<<<dim3(1024), dim3(256), 0, stream>>>(O_part, L_part, out);
}

// Round 8
// 258.700 us; speedup vs baseline: 1.3126x; 1.0040x over previous
//
#include <hip/hip_runtime.h>

// MaskedAttentionHead: y = softmax((q@Wq+bq)(k@Wk+bk)^T/8 * m_row) @ (v@Wv+bv)
// B=4 S=4096 D=1024 DK=64. fp32 in/out, bf16 MFMA intermediates, fp32 accum.
// m/8*log2e folded into Q-proj -> mask-free exp2 flash attn, no max-subtract
// (scores statically bounded), additive split-K (4 splits).
// R14: budget now proj 82 / attn 43 / rest small. proj and attn both plateau
// at ~2.5-3 TB/s DELIVERED across 5 structural variants; the one untested
// axis is pipeline DEPTH (both use 1-deep prefetch: loads waited ~400cy
// after issue vs ~900cy HBM latency -> barrier-coupled convoy). This round:
// proj X-prefetch goes 2-deep (xrA/xrB named sets, kc fully unrolled, W
// stays 1-deep L2-resident). +16 VGPR (40->56, <64 cliff). All else = R13.

typedef __attribute__((ext_vector_type(8))) short short8;   // 8 bf16 = MFMA A/B frag
typedef __attribute__((ext_vector_type(4))) float float4v;  // MFMA C/D frag
typedef __attribute__((ext_vector_type(4))) unsigned int uint4v;

#define DEV static __device__ __forceinline__

DEV unsigned short f2bf(float f) {
  unsigned int x; __builtin_memcpy(&x, &f, 4);
  x += 0x7fff + ((x >> 16) & 1);  // round-to-nearest-even
  return (unsigned short)(x >> 16);
}

// ---------------- kernel 1: W transpose (3 x [1024,64] -> [64,1024] bf16) ---
__global__ __launch_bounds__(256) void transpose_w(
    const float* __restrict__ Wq, const float* __restrict__ Wk,
    const float* __restrict__ Wv, unsigned short* __restrict__ WT) {
  int idx = blockIdx.x * 256 + threadIdx.x;   // over 3*1024*64
  int p = idx >> 16;
  int r = idx & 65535;            // r = k*64 + d  (coalesced read)
  int kk = r >> 6, d = r & 63;
  const float* W = (p == 0) ? Wq : (p == 1) ? Wk : Wv;
  WT[p * 65536 + d * 1024 + kk] = f2bf(W[r]);
}

// ---------------- kernel 2: fused projections (2-deep X prefetch) -----------
// R8 skeleton + 2-deep X pipeline. 32-row tiles, LDS-staged, 6 blocks/CU.
// p=0: qs[b,s,d]  = (q@Wq+bq) * m[b,s]/8 * log2(e)   (row-major, bf16)
// p=1: kh[b,s,d]  = k@Wk+bk                           (row-major)
// p=2: vhT[b,d,s] = (v@Wv+bv)^T   (transposed via swapped MFMA operand roles)
__global__ __launch_bounds__(256, 6) void proj_kernel(
    const float* __restrict__ xq, const float* __restrict__ xk,
    const float* __restrict__ xv, const float* __restrict__ mmask,
    const float* __restrict__ bq, const float* __restrict__ bk,
    const float* __restrict__ bv, const unsigned short* __restrict__ WT,
    unsigned short* __restrict__ qs, unsigned short* __restrict__ khh,
    unsigned short* __restrict__ vhT) {
  constexpr int LDSTR = 136;  // 128+8: 16B-aligned rows, 2-way bank alias (free)
  __shared__ __align__(16) unsigned short Xs[32 * LDSTR];   //  8704 B
  __shared__ __align__(16) unsigned short Ws[64 * LDSTR];   // 17408 B -> 26.1KB

  const int p = blockIdx.x >> 9;        // projection id (0..2)
  const int rt = blockIdx.x & 511;      // 32-row tile id
  const int row0 = rt * 32;             // flat (b,s) row in [0,16384)
  const int t = threadIdx.x;
  const int w = t >> 6, ln = t & 63;
  const int lr = ln & 15, quad = ln >> 4;

  const float* X = (p == 0) ? xq : (p == 1) ? xk : xv;
  const unsigned short* WTp = WT + p * 65536;
  const float* Xbase = X + (size_t)row0 * 1024;

  float4v acc[2];
#pragma unroll
  for (int i = 0; i < 2; ++i) acc[i] = (float4v){0.f, 0.f, 0.f, 0.f};

  const int xr_row = t >> 5, xr_col = (t & 31) * 4;   // col in floats
  const int wr_row = t >> 4, wr_col = (t & 15) * 8;   // col in shorts
  const float* Xsrc = Xbase + (size_t)xr_row * 1024 + xr_col;
  const unsigned short* Wsrc = WTp + (size_t)wr_row * 1024 + wr_col;
  unsigned short* Xdst = &Xs[xr_row * LDSTR + xr_col];
  unsigned short* Wdst = &Ws[wr_row * LDSTR + wr_col];

  float4v xrA[4], xrB[4];  // 2-deep X prefetch (named sets, static indexing)
  uint4v wr[4];            // 1-deep W prefetch (L2-resident, short latency)

#define ISSUE_X(SET_, kc_)                                                 \
  {                                                                        \
    const int k0_ = (kc_) * 128;                                           \
    _Pragma("unroll") for (int i = 0; i < 4; ++i)                          \
      SET_[i] = *(const float4v*)(Xsrc + (size_t)i * 8 * 1024 + k0_);      \
  }
#define ISSUE_W(kc_)                                                       \
  {                                                                        \
    const int k0_ = (kc_) * 128;                                           \
    _Pragma("unroll") for (int i = 0; i < 4; ++i)                          \
      wr[i] = *(const uint4v*)(Wsrc + (size_t)i * 16 * 1024 + k0_);        \
  }
#define XWRITE(SET_)                                                       \
  _Pragma("unroll") for (int i = 0; i < 4; ++i) {                          \
    unsigned short tmp[4];                                                 \
    _Pragma("unroll") for (int j = 0; j < 4; ++j) tmp[j] = f2bf(SET_[i][j]); \
    __builtin_memcpy(Xdst + i * 8 * LDSTR, tmp, 8);                        \
  }

  ISSUE_X(xrA, 0);
  ISSUE_X(xrB, 1);
  ISSUE_W(0);
#pragma unroll
  for (int kc = 0; kc < 8; ++kc) {    // fully unrolled: set choice is static
    if ((kc & 1) == 0) { XWRITE(xrA); } else { XWRITE(xrB); }
#pragma unroll
    for (int i = 0; i < 4; ++i)
      *(uint4v*)(Wdst + i * 16 * LDSTR) = wr[i];
    __syncthreads();
    if (kc < 7) ISSUE_W(kc + 1);
    if (kc < 6) {                     // refill the set just written (2 ahead)
      if ((kc & 1) == 0) { ISSUE_X(xrA, kc + 2); } else { ISSUE_X(xrB, kc + 2); }
    }

    if (p < 2) {
      const int rb = w & 1, cb = w >> 1;
#pragma unroll
      for (int ks = 0; ks < 4; ++ks) {
        short8 af = *(const short8*)&Xs[(rb * 16 + lr) * LDSTR + ks * 32 + quad * 8];
#pragma unroll
        for (int ct = 0; ct < 2; ++ct) {
          short8 bf = *(const short8*)&Ws[(cb * 32 + ct * 16 + lr) * LDSTR + ks * 32 + quad * 8];
          acc[ct] = __builtin_amdgcn_mfma_f32_16x16x32_bf16(af, bf, acc[ct], 0, 0, 0);
        }
      }
    } else {
#pragma unroll
      for (int ks = 0; ks < 4; ++ks) {
        short8 af = *(const short8*)&Ws[(w * 16 + lr) * LDSTR + ks * 32 + quad * 8];
#pragma unroll
        for (int ct = 0; ct < 2; ++ct) {
          short8 bf = *(const short8*)&Xs[(ct * 16 + lr) * LDSTR + ks * 32 + quad * 8];
          acc[ct] = __builtin_amdgcn_mfma_f32_16x16x32_bf16(af, bf, acc[ct], 0, 0, 0);
        }
      }
    }
    __syncthreads();
  }
#undef ISSUE_X
#undef ISSUE_W
#undef XWRITE

  // epilogues; C/D layout: col = lr, row = quad*4 + reg
  if (p == 0) {
    const float L2E8 = 1.4426950408889634f * 0.125f;  // log2(e)/sqrt(64)
    const int rb = w & 1, cb = w >> 1;
#pragma unroll
    for (int r = 0; r < 4; ++r) {
      int sg = row0 + rb * 16 + quad * 4 + r;
      float mv = mmask[sg] * L2E8;
#pragma unroll
      for (int ct = 0; ct < 2; ++ct) {
        int d = cb * 32 + ct * 16 + lr;
        qs[(size_t)sg * 64 + d] = f2bf((acc[ct][r] + bq[d]) * mv);
      }
    }
  } else if (p == 1) {
    const int rb = w & 1, cb = w >> 1;
#pragma unroll
    for (int r = 0; r < 4; ++r) {
      int sg = row0 + rb * 16 + quad * 4 + r;
#pragma unroll
      for (int ct = 0; ct < 2; ++ct) {
        int d = cb * 32 + ct * 16 + lr;
        khh[(size_t)sg * 64 + d] = f2bf(acc[ct][r] + bk[d]);
      }
    }
  } else {
    int b = row0 >> 12, sloc = row0 & 4095;
#pragma unroll
    for (int r = 0; r < 4; ++r) {
      int d = w * 16 + quad * 4 + r;
      float bias = bv[d];
#pragma unroll
      for (int ct = 0; ct < 2; ++ct) {
        int sg = sloc + ct * 16 + lr;
        vhT[(size_t)b * 64 * 4096 + (size_t)d * 4096 + sg] = f2bf(acc[ct][r] + bias);
      }
    }
  }
}

// ---------------- kernel 3: split-K flash attention (staged, 8 waves) ------
// grid = SPLITS * B * (S/128); block = 8 waves = 128 q-rows. Each block
// processes 1024 keys (16 tiles of 64), staging K/V in LDS with one-tile
// register prefetch. Staging = one 16B load/thread/buffer.
#define SPLITS 4
__global__ __launch_bounds__(512) void attn_split(
    const unsigned short* __restrict__ qs, const unsigned short* __restrict__ khh,
    const unsigned short* __restrict__ vhT, float* __restrict__ O_part,
    float* __restrict__ L_part) {
  constexpr int LDSTR = 88;
  __shared__ __align__(16) unsigned short Ks[64 * LDSTR];       // [key][d]  11264B
  __shared__ __align__(16) unsigned short Vs[64 * LDSTR];       // [d][key]  11264B
  __shared__ __align__(16) unsigned short Ps[8 * 16 * LDSTR];   // P [q][key] 22528B

  const int split = blockIdx.x >> 7;
  const int rest  = blockIdx.x & 127;
  const int b = rest >> 5;
  const int s0 = (rest & 31) * 128;
  const int t = threadIdx.x, w = t >> 6, ln = t & 63;
  const int lr = ln & 15, quad = ln >> 4;

  // Q A-fragments, held in registers for the whole kernel
  const size_t qrow = (size_t)(b * 4096 + s0 + w * 16 + lr) * 64;
  short8 qf0 = *(const short8*)&qs[qrow + quad * 8];
  short8 qf1 = *(const short8*)&qs[qrow + 32 + quad * 8];

  float Lacc[4] = {0.f, 0.f, 0.f, 0.f};
  float4v O[4];
#pragma unroll
  for (int i = 0; i < 4; ++i) O[i] = (float4v){0.f, 0.f, 0.f, 0.f};

  // staging: 512 threads, 8 threads/row, one 16B chunk each
  const int srow = t >> 3, scol = (t & 7) * 8;
  const unsigned short* Kg = khh + (size_t)b * 4096 * 64;
  const unsigned short* Vg = vhT + (size_t)b * 64 * 4096;
  unsigned short* Pw = Ps + w * 16 * LDSTR;

  uint4v kr, vr;                      // prefetch registers (one each)

#define ISSUE_KV(kt_)                                                       \
  {                                                                         \
    const int k0_ = split * 1024 + (kt_) * 64;                              \
    kr = *(const uint4v*)&Kg[(size_t)(k0_ + srow) * 64 + scol];             \
    vr = *(const uint4v*)&Vg[(size_t)srow * 4096 + k0_ + scol];             \
  }

  ISSUE_KV(0);
  for (int kt = 0; kt < 16; ++kt) {
    *(uint4v*)&Ks[srow * LDSTR + scol] = kr;
    *(uint4v*)&Vs[srow * LDSTR + scol] = vr;
    __syncthreads();
    if (kt < 15) ISSUE_KV(kt + 1);    // overlap next tile's loads with compute

    // S = Q K^T: 16 q-rows x 64 keys per wave
    float4v sc[4];
#pragma unroll
    for (int ct = 0; ct < 4; ++ct) {
      sc[ct] = (float4v){0.f, 0.f, 0.f, 0.f};
      short8 kf0 = *(const short8*)&Ks[(ct * 16 + lr) * LDSTR + quad * 8];
      short8 kf1 = *(const short8*)&Ks[(ct * 16 + lr) * LDSTR + 32 + quad * 8];
      sc[ct] = __builtin_amdgcn_mfma_f32_16x16x32_bf16(qf0, kf0, sc[ct], 0, 0, 0);
      sc[ct] = __builtin_amdgcn_mfma_f32_16x16x32_bf16(qf1, kf1, sc[ct], 0, 0, 0);
    }

    // P = exp2(S), accumulate per-lane row partials (no shuffles, no rescale)
#pragma unroll
    for (int ct = 0; ct < 4; ++ct)
#pragma unroll
      for (int r = 0; r < 4; ++r) {
        float pv = exp2f(sc[ct][r]);
        Lacc[r] += pv;
        Pw[(quad * 4 + r) * LDSTR + ct * 16 + lr] = f2bf(pv);
      }

    __asm__ volatile("s_waitcnt lgkmcnt(0)" ::: "memory");

    short8 pf0 = *(const short8*)&Pw[lr * LDSTR + quad * 8];
    short8 pf1 = *(const short8*)&Pw[lr * LDSTR + 32 + quad * 8];
#pragma unroll
    for (int dt = 0; dt < 4; ++dt) {
      short8 vf0 = *(const short8*)&Vs[(dt * 16 + lr) * LDSTR + quad * 8];
      short8 vf1 = *(const short8*)&Vs[(dt * 16 + lr) * LDSTR + 32 + quad * 8];
      O[dt] = __builtin_amdgcn_mfma_f32_16x16x32_bf16(pf0, vf0, O[dt], 0, 0, 0);
      O[dt] = __builtin_amdgcn_mfma_f32_16x16x32_bf16(pf1, vf1, O[dt], 0, 0, 0);
    }
    __syncthreads();
  }
#undef ISSUE_KV

  // reduce L over the 16 lanes of each quad (once per kernel, not per tile)
#pragma unroll
  for (int r = 0; r < 4; ++r) {
    float s = Lacc[r];
    s += __shfl_xor(s, 1);
    s += __shfl_xor(s, 2);
    s += __shfl_xor(s, 4);
    s += __shfl_xor(s, 8);
    Lacc[r] = s;
  }

  // store partials; C/D layout: col=lr (d), row=quad*4+r (q-row)
#pragma unroll
  for (int r = 0; r < 4; ++r) {
    int prow = b * 4096 + s0 + w * 16 + quad * 4 + r;
    size_t obase = ((size_t)split * 16384 + prow) * 64;
#pragma unroll
    for (int dt = 0; dt < 4; ++dt)
      O_part[obase + dt * 16 + lr] = O[dt][r];
    if (lr == 0) L_part[(size_t)split * 16384 + prow] = Lacc[r];
  }
}

// ---------------- kernel 4: split-K combine (float4-vectorized) -------------
__global__ __launch_bounds__(256) void attn_reduce(
    const float* __restrict__ O_part, const float* __restrict__ L_part,
    float* __restrict__ out) {
  size_t i4 = (size_t)blockIdx.x * 256 + threadIdx.x;   // over 16384*64/4
  size_t row = i4 >> 4;
  float l = L_part[row] + L_part[16384 + row] + L_part[2 * 16384 + row] +
            L_part[3 * 16384 + row];
  const size_t STRIDE = (size_t)16384 * 64 / 4;         // in float4s
  const float4v* OP = (const float4v*)O_part;
  float4v o = OP[i4];
  float4v o1 = OP[i4 + STRIDE];
  float4v o2 = OP[i4 + 2 * STRIDE];
  float4v o3 = OP[i4 + 3 * STRIDE];
  float inv = 1.0f / l;
  float4v r;
#pragma unroll
  for (int j = 0; j < 4; ++j) r[j] = (o[j] + o1[j] + o2[j] + o3[j]) * inv;
  ((float4v*)out)[i4] = r;
}

// ---------------- launch ----------------------------------------------------
extern "C" void kernel_launch(void* const* d_in, const int* in_sizes, int n_in,
                              void* d_out, int out_size, void* d_ws, size_t ws_size,
                              hipStream_t stream) {
  const float* q  = (const float*)d_in[0];
  const float* k  = (const float*)d_in[1];
  const float* v  = (const float*)d_in[2];
  const float* m  = (const float*)d_in[3];
  const float* Wq = (const float*)d_in[4];
  const float* bq = (const float*)d_in[5];
  const float* Wk = (const float*)d_in[6];
  const float* bk = (const float*)d_in[7];
  const float* Wv = (const float*)d_in[8];
  const float* bv = (const float*)d_in[9];
  float* out = (float*)d_out;

  unsigned short* ws16 = (unsigned short*)d_ws;
  unsigned short* WT  = ws16;                     // 3*65536 u16
  unsigned short* qs  = WT + 3 * 65536;           // 16384*64
  unsigned short* kh  = qs + 16384 * 64;          // 16384*64
  unsigned short* vhT = kh + 16384 * 64;          // 4*64*4096
  float* O_part = (float*)(vhT + 16384 * 64);     // SPLITS*16384*64 fp32 (16.8MB)
  float* L_part = O_part + (size_t)SPLITS * 16384 * 64;  // SPLITS*16384 fp32

  transpose_w<<<dim3(768), dim3(256), 0, stream>>>(Wq, Wk, Wv, WT);
  proj_kernel<<<dim3(1536), dim3(256), 0, stream>>>(q, k, v, m, bq, bk, bv, WT,
                                                    qs, kh, vhT);
  attn_split<<<dim3(SPLITS * 128), dim3(512), 0, stream>>>(qs, kh, vhT,
                                                           O_part, L_part);
  attn_reduce<<<dim3(1024), dim3(256), 0, stream>>>(O_part, L_part, out);
}